// Round 1
// baseline (1337.950 us; speedup 1.0000x reference)
//
#include <hip/hip_runtime.h>

#define NN 100000
#define NE 1280000
#define DD 64

// ---------------------------------------------------------------------------
// Scatter: one lane per (edge, feature). 64 lanes of a wave share one edge.
// agg[dst[e]*64 + d] += w[e] * x[src[e]*64 + d]
// ---------------------------------------------------------------------------
__global__ __launch_bounds__(256) void scatter_kernel(
    const float* __restrict__ x,
    const int* __restrict__ src,
    const int* __restrict__ dst,
    const float* __restrict__ w,
    float* __restrict__ agg)
{
    int t = blockIdx.x * blockDim.x + threadIdx.x;
    int e = t >> 6;
    int d = t & 63;
    if (e >= NE) return;
    int s = src[e];
    int q = dst[e];
    float val = w[e] * x[s * DD + d];
    atomicAdd(&agg[q * DD + d], val);
}

// ---------------------------------------------------------------------------
// Fused dual GEMM: out[i,:] = agg[i,:] @ Wrel + brel + x[i,:] @ Wroot  (+ReLU)
// Block = 256 threads = 4 rows x 64 cols. Weights staged in LDS (32 KiB).
// ---------------------------------------------------------------------------
template <bool RELU>
__global__ __launch_bounds__(256) void dual_gemm_kernel(
    const float* __restrict__ agg,
    const float* __restrict__ x,
    const float* __restrict__ Wrel,
    const float* __restrict__ brel,
    const float* __restrict__ Wroot,
    float* __restrict__ out)
{
    __shared__ float sWrel[DD][DD];
    __shared__ float sWroot[DD][DD];

    int tid = threadIdx.x;
    for (int i = tid; i < DD * DD; i += 256) {
        sWrel[i >> 6][i & 63] = Wrel[i];
        sWroot[i >> 6][i & 63] = Wroot[i];
    }
    __syncthreads();

    int r = tid >> 6;        // 0..3 (wave index == row within block)
    int d = tid & 63;        // lane == output column
    int row = blockIdx.x * 4 + r;
    if (row >= NN) return;

    const float* ar = agg + (size_t)row * DD;
    const float* xr = x + (size_t)row * DD;

    float acc = brel[d];
#pragma unroll
    for (int k = 0; k < DD; ++k) {
        acc += ar[k] * sWrel[k][d];
        acc += xr[k] * sWroot[k][d];
    }
    if (RELU) acc = fmaxf(acc, 0.0f);
    out[(size_t)row * DD + d] = acc;
}

extern "C" void kernel_launch(void* const* d_in, const int* in_sizes, int n_in,
                              void* d_out, int out_size, void* d_ws, size_t ws_size,
                              hipStream_t stream)
{
    const float* x     = (const float*)d_in[0];
    const int*   ei    = (const int*)d_in[1];
    const float* w     = (const float*)d_in[2];
    // d_in[3] = batch (unused)
    const float* Wrel1 = (const float*)d_in[4];
    const float* brel1 = (const float*)d_in[5];
    const float* Wroot1= (const float*)d_in[6];
    const float* Wrel2 = (const float*)d_in[7];
    const float* brel2 = (const float*)d_in[8];
    const float* Wroot2= (const float*)d_in[9];
    const float* Wrel3 = (const float*)d_in[10];
    const float* brel3 = (const float*)d_in[11];
    const float* Wroot3= (const float*)d_in[12];

    float* out = (float*)d_out;

    float* agg = (float*)d_ws;            // N*D floats = 25.6 MB
    float* h1  = agg + (size_t)NN * DD;   // N*D floats = 25.6 MB

    const int* src = ei;        // edge_index[0,:]
    const int* dst = ei + NE;   // edge_index[1,:]

    const size_t aggBytes = (size_t)NN * DD * sizeof(float);
    dim3 sblk(256), sgrid((NE * 64 + 255) / 256);
    dim3 gblk(256), ggrid((NN + 3) / 4);

    // ---- Layer 1: x -> h1 ----
    hipMemsetAsync(agg, 0, aggBytes, stream);
    scatter_kernel<<<sgrid, sblk, 0, stream>>>(x, src, dst, w, agg);
    dual_gemm_kernel<true><<<ggrid, gblk, 0, stream>>>(agg, x, Wrel1, brel1, Wroot1, h1);

    // ---- Layer 2: h1 -> out ----
    hipMemsetAsync(agg, 0, aggBytes, stream);
    scatter_kernel<<<sgrid, sblk, 0, stream>>>(h1, src, dst, w, agg);
    dual_gemm_kernel<true><<<ggrid, gblk, 0, stream>>>(agg, h1, Wrel2, brel2, Wroot2, out);

    // ---- Layer 3: out -> out (in-place safe: row read only by its own wave) ----
    hipMemsetAsync(agg, 0, aggBytes, stream);
    scatter_kernel<<<sgrid, sblk, 0, stream>>>(out, src, dst, w, agg);
    dual_gemm_kernel<false><<<ggrid, gblk, 0, stream>>>(agg, out, Wrel3, brel3, Wroot3, out);
}

// Round 2
// 896.644 us; speedup vs baseline: 1.4922x; 1.4922x over previous
//
#include <hip/hip_runtime.h>

#define NN 100000
#define NE 1280000
#define DD 64
#define CHUNK 1024
#define NB ((NN + CHUNK - 1) / CHUNK)   // 98

// ---------------------------------------------------------------------------
// CSR build: histogram of dst -> exclusive scan -> bucket placement.
// ---------------------------------------------------------------------------
__global__ __launch_bounds__(256) void hist_kernel(
    const int* __restrict__ dst, int* __restrict__ deg)
{
    int e = blockIdx.x * 256 + threadIdx.x;   // grid is exact: NE/256
    atomicAdd(&deg[dst[e]], 1);
}

__global__ __launch_bounds__(256) void scan1_kernel(
    const int* __restrict__ deg, int* __restrict__ blockSums)
{
    __shared__ int red[256];
    int b = blockIdx.x, tid = threadIdx.x;
    int i0 = b * CHUNK + tid * 4;
    int s = 0;
#pragma unroll
    for (int t = 0; t < 4; ++t) s += (i0 + t < NN) ? deg[i0 + t] : 0;
    red[tid] = s;
    __syncthreads();
    for (int off = 128; off > 0; off >>= 1) {
        if (tid < off) red[tid] += red[tid + off];
        __syncthreads();
    }
    if (tid == 0) blockSums[b] = red[0];
}

__global__ __launch_bounds__(128) void scan2_kernel(
    int* __restrict__ blockSums, int* __restrict__ rowptr)
{
    __shared__ int sd[128];
    int tid = threadIdx.x;
    int v = (tid < NB) ? blockSums[tid] : 0;
    sd[tid] = v;
    __syncthreads();
    for (int off = 1; off < 128; off <<= 1) {
        int t = (tid >= off) ? sd[tid - off] : 0;
        __syncthreads();
        sd[tid] += t;
        __syncthreads();
    }
    if (tid < NB) blockSums[tid] = sd[tid] - v;   // exclusive
    if (tid == 0) rowptr[NN] = NE;
}

__global__ __launch_bounds__(256) void scan3_kernel(
    const int* __restrict__ deg, const int* __restrict__ blockSums,
    int* __restrict__ rowptr, int* __restrict__ cursor)
{
    __shared__ int sd[256];
    int b = blockIdx.x, tid = threadIdx.x;
    int i0 = b * CHUNK + tid * 4;
    int v[4];
    int s = 0;
#pragma unroll
    for (int t = 0; t < 4; ++t) { v[t] = (i0 + t < NN) ? deg[i0 + t] : 0; s += v[t]; }
    sd[tid] = s;
    __syncthreads();
    for (int off = 1; off < 256; off <<= 1) {
        int t = (tid >= off) ? sd[tid - off] : 0;
        __syncthreads();
        sd[tid] += t;
        __syncthreads();
    }
    int excl = sd[tid] - s;
    int run = blockSums[b] + excl;
#pragma unroll
    for (int t = 0; t < 4; ++t) {
        if (i0 + t < NN) { rowptr[i0 + t] = run; cursor[i0 + t] = run; }
        run += v[t];
    }
}

__global__ __launch_bounds__(256) void place_kernel(
    const int* __restrict__ src, const int* __restrict__ dst,
    const float* __restrict__ w, int* __restrict__ cursor,
    int2* __restrict__ ebuf)
{
    int e = blockIdx.x * 256 + threadIdx.x;   // grid exact
    int d = dst[e];
    int p = atomicAdd(&cursor[d], 1);
    ebuf[p] = make_int2(src[e], __float_as_int(w[e]));
}

// ---------------------------------------------------------------------------
// Fused GraphConv: per node, agg = sum_{j in in(node)} w_j * h[src_j]  (CSR
// gather, or read precomputed agg when GATHER=false), then
// out = agg @ Wrel + brel + h @ Wroot (+ReLU).
// Block = 256 thr = 4 waves; 16 nodes/block (wave computes 4 nodes together
// to amortize weight LDS reads). Grid 6250 (exact).
// ---------------------------------------------------------------------------
template <bool RELU, bool GATHER>
__global__ __launch_bounds__(256) void gconv_kernel(
    const float* __restrict__ h,
    const float* __restrict__ aggbuf,
    const int* __restrict__ rowptr,
    const int2* __restrict__ ebuf,
    const float* __restrict__ Wrel,
    const float* __restrict__ brel,
    const float* __restrict__ Wroot,
    float* __restrict__ out)
{
    __shared__ float sWrel[DD][DD];    // 16 KB, [k][d]
    __shared__ float sWroot[DD][DD];   // 16 KB
    __shared__ float sAgg[16][DD];     // 4 KB, [slot][k]
    __shared__ float sX[16][DD];       // 4 KB

    int tid = threadIdx.x;
    {
        const float4* wa = (const float4*)Wrel;
        const float4* wb = (const float4*)Wroot;
        float4* sa = (float4*)&sWrel[0][0];
        float4* sb = (float4*)&sWroot[0][0];
#pragma unroll
        for (int i = 0; i < 4; ++i) {
            sa[tid + 256 * i] = wa[tid + 256 * i];
            sb[tid + 256 * i] = wb[tid + 256 * i];
        }
    }

    int lane = tid & 63;
    int wv = tid >> 6;            // 0..3
    int base = blockIdx.x * 16;
    int slot0 = wv * 4;

    // ---- phase 1: aggregate 4 nodes per wave into LDS (same-wave use only)
#pragma unroll
    for (int s = 0; s < 4; ++s) {
        int node = base + slot0 + s;
        float acc;
        if (GATHER) {
            acc = 0.f;
            int beg = rowptr[node], end = rowptr[node + 1];
            for (int j = beg; j < end; ++j) {
                int2 er = ebuf[j];
                acc = fmaf(__int_as_float(er.y), h[(size_t)er.x * DD + lane], acc);
            }
        } else {
            acc = aggbuf[(size_t)node * DD + lane];
        }
        sAgg[slot0 + s][lane] = acc;
        sX[slot0 + s][lane] = h[(size_t)node * DD + lane];
    }
    __syncthreads();   // weights ready (sAgg/sX are same-wave)

    // ---- phase 2: dual GEMM for 4 nodes
    float a1[4], a2[4];
    float bias = brel[lane];
#pragma unroll
    for (int s = 0; s < 4; ++s) { a1[s] = bias; a2[s] = 0.f; }

    const float4* sAgg4 = (const float4*)&sAgg[0][0];   // [16][16]
    const float4* sX4   = (const float4*)&sX[0][0];

#pragma unroll 4
    for (int k4 = 0; k4 < 16; ++k4) {
        float4 ag[4], xx[4];
#pragma unroll
        for (int s = 0; s < 4; ++s) {
            ag[s] = sAgg4[(slot0 + s) * 16 + k4];
            xx[s] = sX4[(slot0 + s) * 16 + k4];
        }
#pragma unroll
        for (int kk = 0; kk < 4; ++kk) {
            float wr = sWrel[k4 * 4 + kk][lane];
            float wo = sWroot[k4 * 4 + kk][lane];
#pragma unroll
            for (int s = 0; s < 4; ++s) {
                a1[s] = fmaf(((const float*)&ag[s])[kk], wr, a1[s]);
                a2[s] = fmaf(((const float*)&xx[s])[kk], wo, a2[s]);
            }
        }
    }

#pragma unroll
    for (int s = 0; s < 4; ++s) {
        int node = base + slot0 + s;
        float v = a1[s] + a2[s];
        if (RELU) v = fmaxf(v, 0.f);
        out[(size_t)node * DD + lane] = v;
    }
}

// ---------------------------------------------------------------------------
// Standalone CSR gather -> agg (for layer 3's out-of-place aggregation).
// Wave per node, grid 25000 (exact).
// ---------------------------------------------------------------------------
__global__ __launch_bounds__(256) void csr_agg_kernel(
    const float* __restrict__ h,
    const int* __restrict__ rowptr,
    const int2* __restrict__ ebuf,
    float* __restrict__ agg)
{
    int tid = threadIdx.x;
    int lane = tid & 63;
    int node = blockIdx.x * 4 + (tid >> 6);
    float acc = 0.f;
    int beg = rowptr[node], end = rowptr[node + 1];
    for (int j = beg; j < end; ++j) {
        int2 er = ebuf[j];
        acc = fmaf(__int_as_float(er.y), h[(size_t)er.x * DD + lane], acc);
    }
    agg[(size_t)node * DD + lane] = acc;
}

extern "C" void kernel_launch(void* const* d_in, const int* in_sizes, int n_in,
                              void* d_out, int out_size, void* d_ws, size_t ws_size,
                              hipStream_t stream)
{
    const float* x     = (const float*)d_in[0];
    const int*   ei    = (const int*)d_in[1];
    const float* w     = (const float*)d_in[2];
    const float* Wrel1 = (const float*)d_in[4];
    const float* brel1 = (const float*)d_in[5];
    const float* Wroot1= (const float*)d_in[6];
    const float* Wrel2 = (const float*)d_in[7];
    const float* brel2 = (const float*)d_in[8];
    const float* Wroot2= (const float*)d_in[9];
    const float* Wrel3 = (const float*)d_in[10];
    const float* brel3 = (const float*)d_in[11];
    const float* Wroot3= (const float*)d_in[12];

    float* out = (float*)d_out;

    // workspace layout: ebuf (8B-aligned first), h1, then int arrays
    char* ws = (char*)d_ws;
    int2*  ebuf   = (int2*)ws;                          ws += (size_t)NE * 8;
    float* h1     = (float*)ws;                         ws += (size_t)NN * DD * 4;
    int*   deg    = (int*)ws;                           ws += (size_t)NN * 4;
    int*   rowptr = (int*)ws;                           ws += (size_t)(NN + 1) * 4;
    int*   cursor = (int*)ws;                           ws += (size_t)NN * 4;
    int*   blockSums = (int*)ws;

    const int* src = ei;
    const int* dst = ei + NE;

    // ---- CSR build (per launch; ws is re-poisoned every call)
    hipMemsetAsync(deg, 0, (size_t)NN * 4, stream);
    hist_kernel <<<NE / 256, 256, 0, stream>>>(dst, deg);
    scan1_kernel<<<NB, 256, 0, stream>>>(deg, blockSums);
    scan2_kernel<<<1, 128, 0, stream>>>(blockSums, rowptr);
    scan3_kernel<<<NB, 256, 0, stream>>>(deg, blockSums, rowptr, cursor);
    place_kernel<<<NE / 256, 256, 0, stream>>>(src, dst, w, cursor, ebuf);

    // ---- Layer 1 (fused gather+GEMM): x -> h1
    gconv_kernel<true, true><<<NN / 16, 256, 0, stream>>>(
        x, nullptr, rowptr, ebuf, Wrel1, brel1, Wroot1, h1);

    // ---- Layer 2 (fused): h1 -> out
    gconv_kernel<true, true><<<NN / 16, 256, 0, stream>>>(
        h1, nullptr, rowptr, ebuf, Wrel2, brel2, Wroot2, out);

    // ---- Layer 3: two-phase (fused gather in-place on `out` would race).
    // gather out -> h1 (agg), then row-local dual GEMM out,h1 -> out.
    csr_agg_kernel<<<NN / 4, 256, 0, stream>>>(out, rowptr, ebuf, h1);
    gconv_kernel<false, false><<<NN / 16, 256, 0, stream>>>(
        out, h1, rowptr, ebuf, Wrel3, brel3, Wroot3, out);
}

// Round 3
// 536.760 us; speedup vs baseline: 2.4926x; 1.6705x over previous
//
#include <hip/hip_runtime.h>

#define NN 100000
#define NE 1280000
#define DD 64
#define CHUNK 1024
#define NB ((NN + CHUNK - 1) / CHUNK)   // 98

// ---------------------------------------------------------------------------
// CSR build: histogram of dst -> exclusive scan -> bucket placement.
// ---------------------------------------------------------------------------
__global__ __launch_bounds__(256) void hist_kernel(
    const int* __restrict__ dst, int* __restrict__ deg)
{
    int e = blockIdx.x * 256 + threadIdx.x;   // grid is exact: NE/256
    atomicAdd(&deg[dst[e]], 1);
}

__global__ __launch_bounds__(256) void scan1_kernel(
    const int* __restrict__ deg, int* __restrict__ blockSums)
{
    __shared__ int red[256];
    int b = blockIdx.x, tid = threadIdx.x;
    int i0 = b * CHUNK + tid * 4;
    int s = 0;
#pragma unroll
    for (int t = 0; t < 4; ++t) s += (i0 + t < NN) ? deg[i0 + t] : 0;
    red[tid] = s;
    __syncthreads();
    for (int off = 128; off > 0; off >>= 1) {
        if (tid < off) red[tid] += red[tid + off];
        __syncthreads();
    }
    if (tid == 0) blockSums[b] = red[0];
}

__global__ __launch_bounds__(128) void scan2_kernel(
    int* __restrict__ blockSums, int* __restrict__ rowptr)
{
    __shared__ int sd[128];
    int tid = threadIdx.x;
    int v = (tid < NB) ? blockSums[tid] : 0;
    sd[tid] = v;
    __syncthreads();
    for (int off = 1; off < 128; off <<= 1) {
        int t = (tid >= off) ? sd[tid - off] : 0;
        __syncthreads();
        sd[tid] += t;
        __syncthreads();
    }
    if (tid < NB) blockSums[tid] = sd[tid] - v;   // exclusive
    if (tid == 0) rowptr[NN] = NE;
}

__global__ __launch_bounds__(256) void scan3_kernel(
    const int* __restrict__ deg, const int* __restrict__ blockSums,
    int* __restrict__ rowptr, int* __restrict__ cursor)
{
    __shared__ int sd[256];
    int b = blockIdx.x, tid = threadIdx.x;
    int i0 = b * CHUNK + tid * 4;
    int v[4];
    int s = 0;
#pragma unroll
    for (int t = 0; t < 4; ++t) { v[t] = (i0 + t < NN) ? deg[i0 + t] : 0; s += v[t]; }
    sd[tid] = s;
    __syncthreads();
    for (int off = 1; off < 256; off <<= 1) {
        int t = (tid >= off) ? sd[tid - off] : 0;
        __syncthreads();
        sd[tid] += t;
        __syncthreads();
    }
    int excl = sd[tid] - s;
    int run = blockSums[b] + excl;
#pragma unroll
    for (int t = 0; t < 4; ++t) {
        if (i0 + t < NN) { rowptr[i0 + t] = run; cursor[i0 + t] = run; }
        run += v[t];
    }
}

__global__ __launch_bounds__(256) void place_kernel(
    const int* __restrict__ src, const int* __restrict__ dst,
    const float* __restrict__ w, int* __restrict__ cursor,
    int2* __restrict__ ebuf)
{
    int e = blockIdx.x * 256 + threadIdx.x;   // grid exact
    int d = dst[e];
    int p = atomicAdd(&cursor[d], 1);
    ebuf[p] = make_int2(src[e], __float_as_int(w[e]));
}

// ---------------------------------------------------------------------------
// CSR gather: agg[node,:] = sum_j w_j * h[src_j,:]. Wave per node, no LDS
// (full occupancy). Unroll-4 with independent accumulators -> 4 feature
// loads in flight. beg/end scalarized so edge-record loads go scalar.
// Grid 25000 (exact).
// ---------------------------------------------------------------------------
__global__ __launch_bounds__(256) void csr_agg_kernel(
    const float* __restrict__ h,
    const int* __restrict__ rowptr,
    const int2* __restrict__ ebuf,
    float* __restrict__ agg)
{
    int lane = threadIdx.x & 63;
    int node = blockIdx.x * 4 + (threadIdx.x >> 6);
    int beg = __builtin_amdgcn_readfirstlane(rowptr[node]);
    int end = __builtin_amdgcn_readfirstlane(rowptr[node + 1]);

    float a0 = 0.f, a1 = 0.f, a2 = 0.f, a3 = 0.f;
    int j = beg;
    for (; j + 4 <= end; j += 4) {
        int2 e0 = ebuf[j];
        int2 e1 = ebuf[j + 1];
        int2 e2 = ebuf[j + 2];
        int2 e3 = ebuf[j + 3];
        float v0 = h[(size_t)e0.x * DD + lane];
        float v1 = h[(size_t)e1.x * DD + lane];
        float v2 = h[(size_t)e2.x * DD + lane];
        float v3 = h[(size_t)e3.x * DD + lane];
        a0 = fmaf(__int_as_float(e0.y), v0, a0);
        a1 = fmaf(__int_as_float(e1.y), v1, a1);
        a2 = fmaf(__int_as_float(e2.y), v2, a2);
        a3 = fmaf(__int_as_float(e3.y), v3, a3);
    }
    for (; j < end; ++j) {
        int2 e0 = ebuf[j];
        a0 = fmaf(__int_as_float(e0.y), h[(size_t)e0.x * DD + lane], a0);
    }
    agg[(size_t)node * DD + lane] = (a0 + a1) + (a2 + a3);
}

// ---------------------------------------------------------------------------
// Streaming dual GEMM: out[i,:] = agg[i,:] @ Wrel + brel + h[i,:] @ Wroot
// (+ReLU). Block = 256 thr = 4 waves, 16 nodes/block, weights in LDS.
// In-place safe for out==agg or out==h: every agg/h row is staged to LDS by
// its own block (phase 1, pre-sync) before any write (phase 2).
// Grid 6250 (exact).
// ---------------------------------------------------------------------------
template <bool RELU>
__global__ __launch_bounds__(256) void dual_gemm_kernel(
    const float* __restrict__ aggbuf,
    const float* __restrict__ h,
    const float* __restrict__ Wrel,
    const float* __restrict__ brel,
    const float* __restrict__ Wroot,
    float* __restrict__ out)
{
    __shared__ float sWrel[DD][DD];    // 16 KB, [k][d]
    __shared__ float sWroot[DD][DD];   // 16 KB
    __shared__ float sAgg[16][DD];     // 4 KB, [slot][k]
    __shared__ float sX[16][DD];       // 4 KB

    int tid = threadIdx.x;
    {
        const float4* wa = (const float4*)Wrel;
        const float4* wb = (const float4*)Wroot;
        float4* sa = (float4*)&sWrel[0][0];
        float4* sb = (float4*)&sWroot[0][0];
#pragma unroll
        for (int i = 0; i < 4; ++i) {
            sa[tid + 256 * i] = wa[tid + 256 * i];
            sb[tid + 256 * i] = wb[tid + 256 * i];
        }
    }

    int lane = tid & 63;
    int wv = tid >> 6;
    int base = blockIdx.x * 16;
    int slot0 = wv * 4;

    // phase 1: stage this wave's 4 agg rows + 4 h rows into LDS
#pragma unroll
    for (int s = 0; s < 4; ++s) {
        int node = base + slot0 + s;
        sAgg[slot0 + s][lane] = aggbuf[(size_t)node * DD + lane];
        sX[slot0 + s][lane]   = h[(size_t)node * DD + lane];
    }
    __syncthreads();

    // phase 2: dual GEMM for 4 nodes
    float r1[4], r2[4];
    float bias = brel[lane];
#pragma unroll
    for (int s = 0; s < 4; ++s) { r1[s] = bias; r2[s] = 0.f; }

    const float4* sAgg4 = (const float4*)&sAgg[0][0];   // [16][16] float4
    const float4* sX4   = (const float4*)&sX[0][0];

#pragma unroll 4
    for (int k4 = 0; k4 < 16; ++k4) {
        float4 ag[4], xx[4];
#pragma unroll
        for (int s = 0; s < 4; ++s) {
            ag[s] = sAgg4[(slot0 + s) * 16 + k4];
            xx[s] = sX4[(slot0 + s) * 16 + k4];
        }
#pragma unroll
        for (int kk = 0; kk < 4; ++kk) {
            float wr = sWrel[k4 * 4 + kk][lane];
            float wo = sWroot[k4 * 4 + kk][lane];
#pragma unroll
            for (int s = 0; s < 4; ++s) {
                r1[s] = fmaf(((const float*)&ag[s])[kk], wr, r1[s]);
                r2[s] = fmaf(((const float*)&xx[s])[kk], wo, r2[s]);
            }
        }
    }

#pragma unroll
    for (int s = 0; s < 4; ++s) {
        int node = base + slot0 + s;
        float v = r1[s] + r2[s];
        if (RELU) v = fmaxf(v, 0.f);
        out[(size_t)node * DD + lane] = v;
    }
}

extern "C" void kernel_launch(void* const* d_in, const int* in_sizes, int n_in,
                              void* d_out, int out_size, void* d_ws, size_t ws_size,
                              hipStream_t stream)
{
    const float* x     = (const float*)d_in[0];
    const int*   ei    = (const int*)d_in[1];
    const float* w     = (const float*)d_in[2];
    const float* Wrel1 = (const float*)d_in[4];
    const float* brel1 = (const float*)d_in[5];
    const float* Wroot1= (const float*)d_in[6];
    const float* Wrel2 = (const float*)d_in[7];
    const float* brel2 = (const float*)d_in[8];
    const float* Wroot2= (const float*)d_in[9];
    const float* Wrel3 = (const float*)d_in[10];
    const float* brel3 = (const float*)d_in[11];
    const float* Wroot3= (const float*)d_in[12];

    float* out = (float*)d_out;

    // workspace layout
    char* ws = (char*)d_ws;
    int2*  ebuf   = (int2*)ws;                          ws += (size_t)NE * 8;
    float* bufA   = (float*)ws;                         ws += (size_t)NN * DD * 4;
    int*   deg    = (int*)ws;                           ws += (size_t)NN * 4;
    int*   rowptr = (int*)ws;                           ws += (size_t)(NN + 1) * 4;
    int*   cursor = (int*)ws;                           ws += (size_t)NN * 4;
    int*   blockSums = (int*)ws;

    const int* src = ei;
    const int* dst = ei + NE;

    // ---- CSR build (per launch; ws is re-poisoned every call)
    hipMemsetAsync(deg, 0, (size_t)NN * 4, stream);
    hist_kernel <<<NE / 256, 256, 0, stream>>>(dst, deg);
    scan1_kernel<<<NB, 256, 0, stream>>>(deg, blockSums);
    scan2_kernel<<<1, 128, 0, stream>>>(blockSums, rowptr);
    scan3_kernel<<<NB, 256, 0, stream>>>(deg, blockSums, rowptr, cursor);
    place_kernel<<<NE / 256, 256, 0, stream>>>(src, dst, w, cursor, ebuf);

    // ---- Layer 1: gather(x)->out ; gemm(out, x)->bufA  [ReLU]
    csr_agg_kernel<<<NN / 4, 256, 0, stream>>>(x, rowptr, ebuf, out);
    dual_gemm_kernel<true><<<NN / 16, 256, 0, stream>>>(out, x, Wrel1, brel1, Wroot1, bufA);

    // ---- Layer 2: gather(bufA)->out ; gemm(out, bufA)->out  [ReLU, in-place agg]
    csr_agg_kernel<<<NN / 4, 256, 0, stream>>>(bufA, rowptr, ebuf, out);
    dual_gemm_kernel<true><<<NN / 16, 256, 0, stream>>>(out, bufA, Wrel2, brel2, Wroot2, out);

    // ---- Layer 3: gather(out)->bufA ; gemm(bufA, out)->out  [in-place h]
    csr_agg_kernel<<<NN / 4, 256, 0, stream>>>(out, rowptr, ebuf, bufA);
    dual_gemm_kernel<false><<<NN / 16, 256, 0, stream>>>(bufA, out, Wrel3, brel3, Wroot3, out);
}

// Round 4
// 490.283 us; speedup vs baseline: 2.7289x; 1.0948x over previous
//
#include <hip/hip_runtime.h>
#include <hip/hip_bf16.h>

#define NN 100000
#define NE 1280000
#define DD 64
#define NRANGE 98            // ceil(NN/1024)

static __device__ __forceinline__ unsigned short f2bf(float f) {
    __hip_bfloat16 h = __float2bfloat16(f);
    return *reinterpret_cast<unsigned short*>(&h);
}

// ---------------------------------------------------------------------------
// x (fp32) -> bf16 copy. Grid 6250 x 256, 4 elems/thread (exact: 6.4M).
// ---------------------------------------------------------------------------
__global__ __launch_bounds__(256) void f32_to_bf16_kernel(
    const float* __restrict__ in, unsigned short* __restrict__ out)
{
    int i = (blockIdx.x * 256 + threadIdx.x) * 4;
    float4 v = *(const float4*)(in + i);
    ushort4 o;
    o.x = f2bf(v.x); o.y = f2bf(v.y); o.z = f2bf(v.z); o.w = f2bf(v.w);
    *(ushort4*)(out + i) = o;
}

// ---------------------------------------------------------------------------
// Range histogram: count edges per 1024-node dst range. LDS-staged, one
// global atomic per (block, range). Grid 1250 (exact: 1250*1024 = NE).
// ---------------------------------------------------------------------------
__global__ __launch_bounds__(256) void hist2_kernel(
    const int* __restrict__ dst, int* __restrict__ rangeCnt)
{
    __shared__ int h[128];
    int tid = threadIdx.x;
    if (tid < 128) h[tid] = 0;
    __syncthreads();
    int e0 = blockIdx.x * 1024 + tid * 4;
    int4 d4 = *(const int4*)(dst + e0);
    atomicAdd(&h[d4.x >> 10], 1);
    atomicAdd(&h[d4.y >> 10], 1);
    atomicAdd(&h[d4.z >> 10], 1);
    atomicAdd(&h[d4.w >> 10], 1);
    __syncthreads();
    if (tid < NRANGE && h[tid]) atomicAdd(&rangeCnt[tid], h[tid]);
}

// ---------------------------------------------------------------------------
// Exclusive scan of 98 range counts -> rangeBase[99] + gcur (P1 cursors).
// ---------------------------------------------------------------------------
__global__ __launch_bounds__(128) void scan98_kernel(
    const int* __restrict__ rangeCnt, int* __restrict__ rangeBase,
    int* __restrict__ gcur, int* __restrict__ rowptr)
{
    __shared__ int sd[128];
    int tid = threadIdx.x;
    int v = (tid < NRANGE) ? rangeCnt[tid] : 0;
    sd[tid] = v;
    __syncthreads();
    for (int o = 1; o < 128; o <<= 1) {
        int t = (tid >= o) ? sd[tid - o] : 0;
        __syncthreads();
        sd[tid] += t;
        __syncthreads();
    }
    if (tid < NRANGE) { int ex = sd[tid] - v; rangeBase[tid] = ex; gcur[tid] = ex; }
    if (tid == 0) { rangeBase[NRANGE] = NE; rowptr[NN] = NE; }
}

// ---------------------------------------------------------------------------
// P1: coarse bin edges by dst range with block-synchronous LDS staging.
// 1024 edges/block, records grouped per range before global write -> runs of
// ~10 records (84 B) instead of random 8 B scatter. Grid 1250 (exact).
// rec.x = src | (dst&1023)<<17 ; rec.y = w bits.
// ---------------------------------------------------------------------------
__global__ __launch_bounds__(256) void p1_bin_kernel(
    const int* __restrict__ src, const int* __restrict__ dst,
    const float* __restrict__ w, int* __restrict__ gcur,
    int2* __restrict__ ecoarse)
{
    __shared__ int2 stage[1024];
    __shared__ unsigned char sbkt[1024];
    __shared__ int cnt[128], ofs[128], gpos[128], sd[128];

    int tid = threadIdx.x;
    int e0 = blockIdx.x * 1024 + tid * 4;
    int4   s4 = *(const int4*)(src + e0);
    int4   d4 = *(const int4*)(dst + e0);
    float4 w4 = *(const float4*)(w + e0);

    if (tid < 128) cnt[tid] = 0;
    __syncthreads();

    int ss[4] = {s4.x, s4.y, s4.z, s4.w};
    int dd[4] = {d4.x, d4.y, d4.z, d4.w};
    float ww[4] = {w4.x, w4.y, w4.z, w4.w};
    int b[4], p[4];
#pragma unroll
    for (int i = 0; i < 4; ++i) {
        b[i] = dd[i] >> 10;
        p[i] = atomicAdd(&cnt[b[i]], 1);
    }
    __syncthreads();

    // exclusive scan of cnt[0..127] + global space reservation
    int cv = (tid < 128) ? cnt[tid] : 0;
    if (tid < 128) sd[tid] = cv;
    __syncthreads();
    for (int o = 1; o < 128; o <<= 1) {
        int t = (tid >= o && tid < 128) ? sd[tid - o] : 0;
        __syncthreads();
        if (tid < 128) sd[tid] += t;
        __syncthreads();
    }
    if (tid < 128) ofs[tid] = sd[tid] - cv;
    if (tid < NRANGE && cv > 0) gpos[tid] = atomicAdd(&gcur[tid], cv);
    __syncthreads();

    // stage grouped by range
#pragma unroll
    for (int i = 0; i < 4; ++i) {
        int slot = ofs[b[i]] + p[i];
        stage[slot] = make_int2(ss[i] | ((dd[i] & 1023) << 17), __float_as_int(ww[i]));
        sbkt[slot] = (unsigned char)b[i];
    }
    __syncthreads();

    // write out grouped runs
    for (int j = tid; j < 1024; j += 256) {
        int bb = sbkt[j];
        ecoarse[gpos[bb] + (j - ofs[bb])] = stage[j];
    }
}

// ---------------------------------------------------------------------------
// P2: per range (block r owns nodes [r*1024, r*1024+1024)): pass A counts
// per-node degrees in LDS, LDS scan -> rowptr + cursors, pass B places edges
// into ebuf within the range's L2-resident window (full-line writebacks).
// Grid NRANGE.
// ---------------------------------------------------------------------------
__global__ __launch_bounds__(256) void p2_place_kernel(
    const int2* __restrict__ ecoarse, const int* __restrict__ rangeBase,
    int* __restrict__ rowptr, int2* __restrict__ ebuf)
{
    __shared__ int cnt[1024];
    __shared__ int ssum[256];
    int r = blockIdx.x, tid = threadIdx.x;
    int beg = rangeBase[r], end = rangeBase[r + 1];

    for (int i = tid; i < 1024; i += 256) cnt[i] = 0;
    __syncthreads();

    // pass A: per-node counts
    for (int j = beg + tid; j < end; j += 256) {
        int2 rec = ecoarse[j];
        atomicAdd(&cnt[(rec.x >> 17) & 1023], 1);
    }
    __syncthreads();

    // LDS scan over 1024 (4 per thread + 256-wide Hillis-Steele)
    int base4 = tid * 4;
    int c0 = cnt[base4], c1 = cnt[base4 + 1], c2 = cnt[base4 + 2], c3 = cnt[base4 + 3];
    int s = c0 + c1 + c2 + c3;
    ssum[tid] = s;
    __syncthreads();
    for (int o = 1; o < 256; o <<= 1) {
        int t = (tid >= o) ? ssum[tid - o] : 0;
        __syncthreads();
        ssum[tid] += t;
        __syncthreads();
    }
    int p0 = beg + ssum[tid] - s;
    int p1 = p0 + c0, p2 = p1 + c1, p3 = p2 + c2;

    int node0 = (r << 10) + base4;
    if (node0 < NN)     rowptr[node0]     = p0;
    if (node0 + 1 < NN) rowptr[node0 + 1] = p1;
    if (node0 + 2 < NN) rowptr[node0 + 2] = p2;
    if (node0 + 3 < NN) rowptr[node0 + 3] = p3;
    cnt[base4] = p0; cnt[base4 + 1] = p1; cnt[base4 + 2] = p2; cnt[base4 + 3] = p3;
    __syncthreads();

    // pass B: place
    for (int j = beg + tid; j < end; j += 256) {
        int2 rec = ecoarse[j];
        int dl = (rec.x >> 17) & 1023;
        int p = atomicAdd(&cnt[dl], 1);
        ebuf[p] = make_int2(rec.x & 0x1FFFF, rec.y);
    }
}

// ---------------------------------------------------------------------------
// CSR gather, fp32 rows (layer 3). Wave per node, unroll-4 MLP. Grid 25000.
// ---------------------------------------------------------------------------
__global__ __launch_bounds__(256) void csr_agg_kernel(
    const float* __restrict__ h, const int* __restrict__ rowptr,
    const int2* __restrict__ ebuf, float* __restrict__ agg)
{
    int lane = threadIdx.x & 63;
    int node = blockIdx.x * 4 + (threadIdx.x >> 6);
    int beg = __builtin_amdgcn_readfirstlane(rowptr[node]);
    int end = __builtin_amdgcn_readfirstlane(rowptr[node + 1]);

    float a0 = 0.f, a1 = 0.f, a2 = 0.f, a3 = 0.f;
    int j = beg;
    for (; j + 4 <= end; j += 4) {
        int2 e0 = ebuf[j], e1 = ebuf[j + 1], e2 = ebuf[j + 2], e3 = ebuf[j + 3];
        float v0 = h[(size_t)e0.x * DD + lane];
        float v1 = h[(size_t)e1.x * DD + lane];
        float v2 = h[(size_t)e2.x * DD + lane];
        float v3 = h[(size_t)e3.x * DD + lane];
        a0 = fmaf(__int_as_float(e0.y), v0, a0);
        a1 = fmaf(__int_as_float(e1.y), v1, a1);
        a2 = fmaf(__int_as_float(e2.y), v2, a2);
        a3 = fmaf(__int_as_float(e3.y), v3, a3);
    }
    for (; j < end; ++j) {
        int2 e0 = ebuf[j];
        a0 = fmaf(__int_as_float(e0.y), h[(size_t)e0.x * DD + lane], a0);
    }
    agg[(size_t)node * DD + lane] = (a0 + a1) + (a2 + a3);
}

// ---------------------------------------------------------------------------
// CSR gather, bf16 rows (layers 1-2): half the line traffic, fp32 accumulate.
// ---------------------------------------------------------------------------
__global__ __launch_bounds__(256) void csr_agg_bf16_kernel(
    const unsigned short* __restrict__ hb, const int* __restrict__ rowptr,
    const int2* __restrict__ ebuf, float* __restrict__ agg)
{
    int lane = threadIdx.x & 63;
    int node = blockIdx.x * 4 + (threadIdx.x >> 6);
    int beg = __builtin_amdgcn_readfirstlane(rowptr[node]);
    int end = __builtin_amdgcn_readfirstlane(rowptr[node + 1]);

    float a0 = 0.f, a1 = 0.f, a2 = 0.f, a3 = 0.f;
    int j = beg;
    for (; j + 4 <= end; j += 4) {
        int2 e0 = ebuf[j], e1 = ebuf[j + 1], e2 = ebuf[j + 2], e3 = ebuf[j + 3];
        unsigned short u0 = hb[(size_t)e0.x * DD + lane];
        unsigned short u1 = hb[(size_t)e1.x * DD + lane];
        unsigned short u2 = hb[(size_t)e2.x * DD + lane];
        unsigned short u3 = hb[(size_t)e3.x * DD + lane];
        a0 = fmaf(__int_as_float(e0.y), __uint_as_float((unsigned)u0 << 16), a0);
        a1 = fmaf(__int_as_float(e1.y), __uint_as_float((unsigned)u1 << 16), a1);
        a2 = fmaf(__int_as_float(e2.y), __uint_as_float((unsigned)u2 << 16), a2);
        a3 = fmaf(__int_as_float(e3.y), __uint_as_float((unsigned)u3 << 16), a3);
    }
    for (; j < end; ++j) {
        int2 e0 = ebuf[j];
        unsigned short u0 = hb[(size_t)e0.x * DD + lane];
        a0 = fmaf(__int_as_float(e0.y), __uint_as_float((unsigned)u0 << 16), a0);
    }
    agg[(size_t)node * DD + lane] = (a0 + a1) + (a2 + a3);
}

// ---------------------------------------------------------------------------
// Streaming dual GEMM (+ optional bf16 side-copy of the output for the next
// layer's gather). In-place safe (rows staged to LDS pre-sync). Grid 6250.
// ---------------------------------------------------------------------------
template <bool RELU, bool DUAL>
__global__ __launch_bounds__(256) void dual_gemm_kernel(
    const float* __restrict__ aggbuf,
    const float* __restrict__ h,
    const float* __restrict__ Wrel,
    const float* __restrict__ brel,
    const float* __restrict__ Wroot,
    float* __restrict__ out,
    unsigned short* __restrict__ outb)
{
    __shared__ float sWrel[DD][DD];
    __shared__ float sWroot[DD][DD];
    __shared__ float sAgg[16][DD];
    __shared__ float sX[16][DD];

    int tid = threadIdx.x;
    {
        const float4* wa = (const float4*)Wrel;
        const float4* wb = (const float4*)Wroot;
        float4* sa = (float4*)&sWrel[0][0];
        float4* sb = (float4*)&sWroot[0][0];
#pragma unroll
        for (int i = 0; i < 4; ++i) {
            sa[tid + 256 * i] = wa[tid + 256 * i];
            sb[tid + 256 * i] = wb[tid + 256 * i];
        }
    }

    int lane = tid & 63;
    int wv = tid >> 6;
    int base = blockIdx.x * 16;
    int slot0 = wv * 4;

#pragma unroll
    for (int s = 0; s < 4; ++s) {
        int node = base + slot0 + s;
        sAgg[slot0 + s][lane] = aggbuf[(size_t)node * DD + lane];
        sX[slot0 + s][lane]   = h[(size_t)node * DD + lane];
    }
    __syncthreads();

    float r1[4], r2[4];
    float bias = brel[lane];
#pragma unroll
    for (int s = 0; s < 4; ++s) { r1[s] = bias; r2[s] = 0.f; }

    const float4* sAgg4 = (const float4*)&sAgg[0][0];
    const float4* sX4   = (const float4*)&sX[0][0];

#pragma unroll 4
    for (int k4 = 0; k4 < 16; ++k4) {
        float4 ag[4], xx[4];
#pragma unroll
        for (int s = 0; s < 4; ++s) {
            ag[s] = sAgg4[(slot0 + s) * 16 + k4];
            xx[s] = sX4[(slot0 + s) * 16 + k4];
        }
#pragma unroll
        for (int kk = 0; kk < 4; ++kk) {
            float wr = sWrel[k4 * 4 + kk][lane];
            float wo = sWroot[k4 * 4 + kk][lane];
#pragma unroll
            for (int s = 0; s < 4; ++s) {
                r1[s] = fmaf(((const float*)&ag[s])[kk], wr, r1[s]);
                r2[s] = fmaf(((const float*)&xx[s])[kk], wo, r2[s]);
            }
        }
    }

#pragma unroll
    for (int s = 0; s < 4; ++s) {
        int node = base + slot0 + s;
        float v = r1[s] + r2[s];
        if (RELU) v = fmaxf(v, 0.f);
        out[(size_t)node * DD + lane] = v;
        if (DUAL) outb[(size_t)node * DD + lane] = f2bf(v);
    }
}

extern "C" void kernel_launch(void* const* d_in, const int* in_sizes, int n_in,
                              void* d_out, int out_size, void* d_ws, size_t ws_size,
                              hipStream_t stream)
{
    const float* x     = (const float*)d_in[0];
    const int*   ei    = (const int*)d_in[1];
    const float* w     = (const float*)d_in[2];
    const float* Wrel1 = (const float*)d_in[4];
    const float* brel1 = (const float*)d_in[5];
    const float* Wroot1= (const float*)d_in[6];
    const float* Wrel2 = (const float*)d_in[7];
    const float* brel2 = (const float*)d_in[8];
    const float* Wroot2= (const float*)d_in[9];
    const float* Wrel3 = (const float*)d_in[10];
    const float* brel3 = (const float*)d_in[11];
    const float* Wroot3= (const float*)d_in[12];

    float* out = (float*)d_out;

    // workspace: ebuf | bufA (aliases ecoarse) | hb | rowptr | small arrays
    char* ws = (char*)d_ws;
    int2*  ebuf    = (int2*)ws;                       ws += (size_t)NE * 8;
    float* bufA    = (float*)ws;
    int2*  ecoarse = (int2*)ws;                       ws += (size_t)NN * DD * 4;  // 25.6MB >= 10.24MB
    unsigned short* hb = (unsigned short*)ws;         ws += (size_t)NN * DD * 2;
    int*   rowptr  = (int*)ws;                        ws += (size_t)(NN + 1) * 4;
    int*   rangeCnt = (int*)ws;                       ws += (size_t)128 * 4;
    int*   rangeBase = (int*)ws;                      ws += (size_t)128 * 4;
    int*   gcur    = (int*)ws;

    const int* src = ei;
    const int* dst = ei + NE;

    // ---- build ----
    f32_to_bf16_kernel<<<6250, 256, 0, stream>>>(x, hb);               // xb
    hipMemsetAsync(rangeCnt, 0, NRANGE * 4, stream);
    hist2_kernel<<<1250, 256, 0, stream>>>(dst, rangeCnt);
    scan98_kernel<<<1, 128, 0, stream>>>(rangeCnt, rangeBase, gcur, rowptr);
    p1_bin_kernel<<<1250, 256, 0, stream>>>(src, dst, w, gcur, ecoarse);
    p2_place_kernel<<<NRANGE, 256, 0, stream>>>(ecoarse, rangeBase, rowptr, ebuf);

    // ---- Layer 1: gather_bf16(xb)->out ; gemm(out, x)->bufA + hb(bf16) ----
    csr_agg_bf16_kernel<<<NN / 4, 256, 0, stream>>>(hb, rowptr, ebuf, out);
    dual_gemm_kernel<true, true><<<NN / 16, 256, 0, stream>>>(
        out, x, Wrel1, brel1, Wroot1, bufA, hb);

    // ---- Layer 2: gather_bf16(hb)->out ; gemm(out, bufA)->out ----
    csr_agg_bf16_kernel<<<NN / 4, 256, 0, stream>>>(hb, rowptr, ebuf, out);
    dual_gemm_kernel<true, false><<<NN / 16, 256, 0, stream>>>(
        out, bufA, Wrel2, brel2, Wroot2, out, nullptr);

    // ---- Layer 3 (fp32 gather for precision): gather(out)->bufA ; gemm->out
    csr_agg_kernel<<<NN / 4, 256, 0, stream>>>(out, rowptr, ebuf, bufA);
    dual_gemm_kernel<false, false><<<NN / 16, 256, 0, stream>>>(
        bufA, out, Wrel3, brel3, Wroot3, out, nullptr);
}

// Round 5
// 486.858 us; speedup vs baseline: 2.7481x; 1.0070x over previous
//
#include <hip/hip_runtime.h>
#include <hip/hip_bf16.h>

#define NN 100000
#define NE 1280000
#define DD 64
#define NRANGE 98            // ceil(NN/1024)
#define GEMM_GRID 1024
#define NGROUPS (NN / 16)    // 6250

static __device__ __forceinline__ unsigned short f2bf(float f) {
    __hip_bfloat16 h = __float2bfloat16(f);
    return *reinterpret_cast<unsigned short*>(&h);
}

// ---------------------------------------------------------------------------
// x (fp32) -> bf16 copy. Grid 6250 x 256, 4 elems/thread (exact: 6.4M).
// ---------------------------------------------------------------------------
__global__ __launch_bounds__(256) void f32_to_bf16_kernel(
    const float* __restrict__ in, unsigned short* __restrict__ out)
{
    int i = (blockIdx.x * 256 + threadIdx.x) * 4;
    float4 v = *(const float4*)(in + i);
    ushort4 o;
    o.x = f2bf(v.x); o.y = f2bf(v.y); o.z = f2bf(v.z); o.w = f2bf(v.w);
    *(ushort4*)(out + i) = o;
}

// ---------------------------------------------------------------------------
// Range histogram: count edges per 1024-node dst range. LDS-staged.
// ---------------------------------------------------------------------------
__global__ __launch_bounds__(256) void hist2_kernel(
    const int* __restrict__ dst, int* __restrict__ rangeCnt)
{
    __shared__ int h[128];
    int tid = threadIdx.x;
    if (tid < 128) h[tid] = 0;
    __syncthreads();
    int e0 = blockIdx.x * 1024 + tid * 4;
    int4 d4 = *(const int4*)(dst + e0);
    atomicAdd(&h[d4.x >> 10], 1);
    atomicAdd(&h[d4.y >> 10], 1);
    atomicAdd(&h[d4.z >> 10], 1);
    atomicAdd(&h[d4.w >> 10], 1);
    __syncthreads();
    if (tid < NRANGE && h[tid]) atomicAdd(&rangeCnt[tid], h[tid]);
}

// ---------------------------------------------------------------------------
// Exclusive scan of 98 range counts -> rangeBase[99] + gcur (P1 cursors).
// ---------------------------------------------------------------------------
__global__ __launch_bounds__(128) void scan98_kernel(
    const int* __restrict__ rangeCnt, int* __restrict__ rangeBase,
    int* __restrict__ gcur, int* __restrict__ rowptr)
{
    __shared__ int sd[128];
    int tid = threadIdx.x;
    int v = (tid < NRANGE) ? rangeCnt[tid] : 0;
    sd[tid] = v;
    __syncthreads();
    for (int o = 1; o < 128; o <<= 1) {
        int t = (tid >= o) ? sd[tid - o] : 0;
        __syncthreads();
        sd[tid] += t;
        __syncthreads();
    }
    if (tid < NRANGE) { int ex = sd[tid] - v; rangeBase[tid] = ex; gcur[tid] = ex; }
    if (tid == 0) { rangeBase[NRANGE] = NE; rowptr[NN] = NE; }
}

// ---------------------------------------------------------------------------
// P1: coarse bin by dst range, block-synchronous LDS staging (grouped runs).
// ---------------------------------------------------------------------------
__global__ __launch_bounds__(256) void p1_bin_kernel(
    const int* __restrict__ src, const int* __restrict__ dst,
    const float* __restrict__ w, int* __restrict__ gcur,
    int2* __restrict__ ecoarse)
{
    __shared__ int2 stage[1024];
    __shared__ unsigned char sbkt[1024];
    __shared__ int cnt[128], ofs[128], gpos[128], sd[128];

    int tid = threadIdx.x;
    int e0 = blockIdx.x * 1024 + tid * 4;
    int4   s4 = *(const int4*)(src + e0);
    int4   d4 = *(const int4*)(dst + e0);
    float4 w4 = *(const float4*)(w + e0);

    if (tid < 128) cnt[tid] = 0;
    __syncthreads();

    int ss[4] = {s4.x, s4.y, s4.z, s4.w};
    int dd[4] = {d4.x, d4.y, d4.z, d4.w};
    float ww[4] = {w4.x, w4.y, w4.z, w4.w};
    int b[4], p[4];
#pragma unroll
    for (int i = 0; i < 4; ++i) {
        b[i] = dd[i] >> 10;
        p[i] = atomicAdd(&cnt[b[i]], 1);
    }
    __syncthreads();

    int cv = (tid < 128) ? cnt[tid] : 0;
    if (tid < 128) sd[tid] = cv;
    __syncthreads();
    for (int o = 1; o < 128; o <<= 1) {
        int t = (tid >= o && tid < 128) ? sd[tid - o] : 0;
        __syncthreads();
        if (tid < 128) sd[tid] += t;
        __syncthreads();
    }
    if (tid < 128) ofs[tid] = sd[tid] - cv;
    if (tid < NRANGE && cv > 0) gpos[tid] = atomicAdd(&gcur[tid], cv);
    __syncthreads();

#pragma unroll
    for (int i = 0; i < 4; ++i) {
        int slot = ofs[b[i]] + p[i];
        stage[slot] = make_int2(ss[i] | ((dd[i] & 1023) << 17), __float_as_int(ww[i]));
        sbkt[slot] = (unsigned char)b[i];
    }
    __syncthreads();

    for (int j = tid; j < 1024; j += 256) {
        int bb = sbkt[j];
        ecoarse[gpos[bb] + (j - ofs[bb])] = stage[j];
    }
}

// ---------------------------------------------------------------------------
// P2: per-range degree count + LDS scan -> rowptr, then place into the
// range's L2-resident ebuf window. Grid NRANGE.
// ---------------------------------------------------------------------------
__global__ __launch_bounds__(256) void p2_place_kernel(
    const int2* __restrict__ ecoarse, const int* __restrict__ rangeBase,
    int* __restrict__ rowptr, int2* __restrict__ ebuf)
{
    __shared__ int cnt[1024];
    __shared__ int ssum[256];
    int r = blockIdx.x, tid = threadIdx.x;
    int beg = rangeBase[r], end = rangeBase[r + 1];

    for (int i = tid; i < 1024; i += 256) cnt[i] = 0;
    __syncthreads();

    for (int j = beg + tid; j < end; j += 256) {
        int2 rec = ecoarse[j];
        atomicAdd(&cnt[(rec.x >> 17) & 1023], 1);
    }
    __syncthreads();

    int base4 = tid * 4;
    int c0 = cnt[base4], c1 = cnt[base4 + 1], c2 = cnt[base4 + 2], c3 = cnt[base4 + 3];
    int s = c0 + c1 + c2 + c3;
    ssum[tid] = s;
    __syncthreads();
    for (int o = 1; o < 256; o <<= 1) {
        int t = (tid >= o) ? ssum[tid - o] : 0;
        __syncthreads();
        ssum[tid] += t;
        __syncthreads();
    }
    int p0 = beg + ssum[tid] - s;
    int p1 = p0 + c0, p2 = p1 + c1, p3 = p2 + c2;

    int node0 = (r << 10) + base4;
    if (node0 < NN)     rowptr[node0]     = p0;
    if (node0 + 1 < NN) rowptr[node0 + 1] = p1;
    if (node0 + 2 < NN) rowptr[node0 + 2] = p2;
    if (node0 + 3 < NN) rowptr[node0 + 3] = p3;
    cnt[base4] = p0; cnt[base4 + 1] = p1; cnt[base4 + 2] = p2; cnt[base4 + 3] = p3;
    __syncthreads();

    for (int j = beg + tid; j < end; j += 256) {
        int2 rec = ecoarse[j];
        int dl = (rec.x >> 17) & 1023;
        int p = atomicAdd(&cnt[dl], 1);
        ebuf[p] = make_int2(rec.x & 0x1FFFF, rec.y);
    }
}

// ---------------------------------------------------------------------------
// CSR gather over bf16 rows (all layers): half the line traffic of fp32,
// fp32 accumulate, unroll-4 MLP. Wave per node, no LDS. Grid 25000.
// ---------------------------------------------------------------------------
__global__ __launch_bounds__(256) void csr_agg_bf16_kernel(
    const unsigned short* __restrict__ hb, const int* __restrict__ rowptr,
    const int2* __restrict__ ebuf, float* __restrict__ agg)
{
    int lane = threadIdx.x & 63;
    int node = blockIdx.x * 4 + (threadIdx.x >> 6);
    int beg = __builtin_amdgcn_readfirstlane(rowptr[node]);
    int end = __builtin_amdgcn_readfirstlane(rowptr[node + 1]);

    float a0 = 0.f, a1 = 0.f, a2 = 0.f, a3 = 0.f;
    int j = beg;
    for (; j + 4 <= end; j += 4) {
        int2 e0 = ebuf[j], e1 = ebuf[j + 1], e2 = ebuf[j + 2], e3 = ebuf[j + 3];
        unsigned short u0 = hb[(size_t)e0.x * DD + lane];
        unsigned short u1 = hb[(size_t)e1.x * DD + lane];
        unsigned short u2 = hb[(size_t)e2.x * DD + lane];
        unsigned short u3 = hb[(size_t)e3.x * DD + lane];
        a0 = fmaf(__int_as_float(e0.y), __uint_as_float((unsigned)u0 << 16), a0);
        a1 = fmaf(__int_as_float(e1.y), __uint_as_float((unsigned)u1 << 16), a1);
        a2 = fmaf(__int_as_float(e2.y), __uint_as_float((unsigned)u2 << 16), a2);
        a3 = fmaf(__int_as_float(e3.y), __uint_as_float((unsigned)u3 << 16), a3);
    }
    for (; j < end; ++j) {
        int2 e0 = ebuf[j];
        unsigned short u0 = hb[(size_t)e0.x * DD + lane];
        a0 = fmaf(__int_as_float(e0.y), __uint_as_float((unsigned)u0 << 16), a0);
    }
    agg[(size_t)node * DD + lane] = (a0 + a1) + (a2 + a3);
}

// ---------------------------------------------------------------------------
// Persistent dual GEMM: grid=1024 blocks, each loops node-groups g, g+1024,..
// Weights loaded once/block (single barrier). Inside the loop each wave uses
// ONLY its own LDS row slots -> no barriers; next group's rows prefetched
// into registers while computing the current group (hides HBM latency).
// In-place safe (out==agg or out==h): every row is read only by its owning
// wave, before that wave stores it.
// ---------------------------------------------------------------------------
template <bool RELU, bool DUAL>
__global__ __launch_bounds__(256) void dual_gemm_kernel(
    const float* __restrict__ aggbuf,
    const float* __restrict__ h,
    const float* __restrict__ Wrel,
    const float* __restrict__ brel,
    const float* __restrict__ Wroot,
    float* __restrict__ out,
    unsigned short* __restrict__ outb)
{
    __shared__ float sWrel[DD][DD];    // [k][d], 16 KB
    __shared__ float sWroot[DD][DD];   // 16 KB
    __shared__ float sAgg[16][DD];     // wave-private slots (4 per wave)
    __shared__ float sX[16][DD];

    int tid = threadIdx.x;
    {
        const float4* wa = (const float4*)Wrel;
        const float4* wb = (const float4*)Wroot;
        float4* sa = (float4*)&sWrel[0][0];
        float4* sb = (float4*)&sWroot[0][0];
#pragma unroll
        for (int i = 0; i < 4; ++i) {
            sa[tid + 256 * i] = wa[tid + 256 * i];
            sb[tid + 256 * i] = wb[tid + 256 * i];
        }
    }

    int lane = tid & 63;
    int wv = tid >> 6;
    int slot0 = wv * 4;
    float bias = brel[lane];
    __syncthreads();   // weights ready; no further barriers

    const float4* sAgg4 = (const float4*)&sAgg[0][0];   // [16][16] float4
    const float4* sX4   = (const float4*)&sX[0][0];

    int g = blockIdx.x;
    // prefetch first group
    float pa[4], px[4];
#pragma unroll
    for (int s = 0; s < 4; ++s) {
        size_t node = (size_t)g * 16 + slot0 + s;
        pa[s] = aggbuf[node * DD + lane];
        px[s] = h[node * DD + lane];
    }

    while (g < NGROUPS) {
        int gn = g + GEMM_GRID;
        // stage prefetched rows into this wave's LDS slots
#pragma unroll
        for (int s = 0; s < 4; ++s) {
            sAgg[slot0 + s][lane] = pa[s];
            sX[slot0 + s][lane]   = px[s];
        }
        // issue next group's loads (independent of compute below)
        if (gn < NGROUPS) {
#pragma unroll
            for (int s = 0; s < 4; ++s) {
                size_t node = (size_t)gn * 16 + slot0 + s;
                pa[s] = aggbuf[node * DD + lane];
                px[s] = h[node * DD + lane];
            }
        }

        float r1[4], r2[4];
#pragma unroll
        for (int s = 0; s < 4; ++s) { r1[s] = bias; r2[s] = 0.f; }

#pragma unroll 4
        for (int k4 = 0; k4 < 16; ++k4) {
            float4 ag[4], xx[4];
#pragma unroll
            for (int s = 0; s < 4; ++s) {
                ag[s] = sAgg4[(slot0 + s) * 16 + k4];
                xx[s] = sX4[(slot0 + s) * 16 + k4];
            }
#pragma unroll
            for (int kk = 0; kk < 4; ++kk) {
                float wr = sWrel[k4 * 4 + kk][lane];
                float wo = sWroot[k4 * 4 + kk][lane];
#pragma unroll
                for (int s = 0; s < 4; ++s) {
                    r1[s] = fmaf(((const float*)&ag[s])[kk], wr, r1[s]);
                    r2[s] = fmaf(((const float*)&xx[s])[kk], wo, r2[s]);
                }
            }
        }

#pragma unroll
        for (int s = 0; s < 4; ++s) {
            size_t node = (size_t)g * 16 + slot0 + s;
            float v = r1[s] + r2[s];
            if (RELU) v = fmaxf(v, 0.f);
            out[node * DD + lane] = v;
            if (DUAL) outb[node * DD + lane] = f2bf(v);
        }
        g = gn;
    }
}

extern "C" void kernel_launch(void* const* d_in, const int* in_sizes, int n_in,
                              void* d_out, int out_size, void* d_ws, size_t ws_size,
                              hipStream_t stream)
{
    const float* x     = (const float*)d_in[0];
    const int*   ei    = (const int*)d_in[1];
    const float* w     = (const float*)d_in[2];
    const float* Wrel1 = (const float*)d_in[4];
    const float* brel1 = (const float*)d_in[5];
    const float* Wroot1= (const float*)d_in[6];
    const float* Wrel2 = (const float*)d_in[7];
    const float* brel2 = (const float*)d_in[8];
    const float* Wroot2= (const float*)d_in[9];
    const float* Wrel3 = (const float*)d_in[10];
    const float* brel3 = (const float*)d_in[11];
    const float* Wroot3= (const float*)d_in[12];

    float* out = (float*)d_out;

    // workspace: ebuf | bufA (aliases ecoarse) | hb | rowptr | small arrays
    char* ws = (char*)d_ws;
    int2*  ebuf    = (int2*)ws;                       ws += (size_t)NE * 8;
    float* bufA    = (float*)ws;
    int2*  ecoarse = (int2*)ws;                       ws += (size_t)NN * DD * 4;
    unsigned short* hb = (unsigned short*)ws;         ws += (size_t)NN * DD * 2;
    int*   rowptr  = (int*)ws;                        ws += (size_t)(NN + 1) * 4;
    int*   rangeCnt = (int*)ws;                       ws += (size_t)128 * 4;
    int*   rangeBase = (int*)ws;                      ws += (size_t)128 * 4;
    int*   gcur    = (int*)ws;

    const int* src = ei;
    const int* dst = ei + NE;

    // ---- build ----
    f32_to_bf16_kernel<<<6250, 256, 0, stream>>>(x, hb);               // xb
    hipMemsetAsync(rangeCnt, 0, NRANGE * 4, stream);
    hist2_kernel<<<1250, 256, 0, stream>>>(dst, rangeCnt);
    scan98_kernel<<<1, 128, 0, stream>>>(rangeCnt, rangeBase, gcur, rowptr);
    p1_bin_kernel<<<1250, 256, 0, stream>>>(src, dst, w, gcur, ecoarse);
    p2_place_kernel<<<NRANGE, 256, 0, stream>>>(ecoarse, rangeBase, rowptr, ebuf);

    // ---- Layer 1: gather(xb)->out ; gemm(out, x)->bufA + hb=bf16(h1) ----
    csr_agg_bf16_kernel<<<NN / 4, 256, 0, stream>>>(hb, rowptr, ebuf, out);
    dual_gemm_kernel<true, true><<<GEMM_GRID, 256, 0, stream>>>(
        out, x, Wrel1, brel1, Wroot1, bufA, hb);

    // ---- Layer 2: gather(hb=h1b)->out ; gemm(out, bufA)->out + hb=bf16(h2)
    csr_agg_bf16_kernel<<<NN / 4, 256, 0, stream>>>(hb, rowptr, ebuf, out);
    dual_gemm_kernel<true, true><<<GEMM_GRID, 256, 0, stream>>>(
        out, bufA, Wrel2, brel2, Wroot2, out, hb);

    // ---- Layer 3: gather(hb=h2b)->bufA ; gemm(bufA, out)->out ----
    csr_agg_bf16_kernel<<<NN / 4, 256, 0, stream>>>(hb, rowptr, ebuf, bufA);
    dual_gemm_kernel<false, false><<<GEMM_GRID, 256, 0, stream>>>(
        bufA, out, Wrel3, brel3, Wroot3, out, nullptr);
}

// Round 6
// 373.635 us; speedup vs baseline: 3.5809x; 1.3030x over previous
//
#include <hip/hip_runtime.h>
#include <hip/hip_bf16.h>

#define NN 100000
#define NE 1280000
#define DD 64
#define NRANGE 98            // ceil(NN/1024)
#define NGROUPS (NN / 16)    // 6250
#define GG 1536              // persistent gemm grid (6 blocks/CU)

typedef __attribute__((ext_vector_type(8))) short bf16x8;
typedef __attribute__((ext_vector_type(4))) float f32x4;

static __device__ __forceinline__ unsigned short f2bf(float f) {
    __hip_bfloat16 h = __float2bfloat16(f);
    return *reinterpret_cast<unsigned short*>(&h);
}

// ---------------------------------------------------------------------------
// x (fp32) -> bf16 copy. Grid 6250 x 256, 4 elems/thread (exact: 6.4M).
// ---------------------------------------------------------------------------
__global__ __launch_bounds__(256) void f32_to_bf16_kernel(
    const float* __restrict__ in, unsigned short* __restrict__ out)
{
    int i = (blockIdx.x * 256 + threadIdx.x) * 4;
    float4 v = *(const float4*)(in + i);
    ushort4 o;
    o.x = f2bf(v.x); o.y = f2bf(v.y); o.z = f2bf(v.z); o.w = f2bf(v.w);
    *(ushort4*)(out + i) = o;
}

// ---------------------------------------------------------------------------
// Range histogram: count edges per 1024-node dst range. LDS-staged.
// ---------------------------------------------------------------------------
__global__ __launch_bounds__(256) void hist2_kernel(
    const int* __restrict__ dst, int* __restrict__ rangeCnt)
{
    __shared__ int h[128];
    int tid = threadIdx.x;
    if (tid < 128) h[tid] = 0;
    __syncthreads();
    int e0 = blockIdx.x * 1024 + tid * 4;
    int4 d4 = *(const int4*)(dst + e0);
    atomicAdd(&h[d4.x >> 10], 1);
    atomicAdd(&h[d4.y >> 10], 1);
    atomicAdd(&h[d4.z >> 10], 1);
    atomicAdd(&h[d4.w >> 10], 1);
    __syncthreads();
    if (tid < NRANGE && h[tid]) atomicAdd(&rangeCnt[tid], h[tid]);
}

// ---------------------------------------------------------------------------
// Exclusive scan of 98 range counts -> rangeBase[99] + gcur (P1 cursors).
// ---------------------------------------------------------------------------
__global__ __launch_bounds__(128) void scan98_kernel(
    const int* __restrict__ rangeCnt, int* __restrict__ rangeBase,
    int* __restrict__ gcur, int* __restrict__ rowptr)
{
    __shared__ int sd[128];
    int tid = threadIdx.x;
    int v = (tid < NRANGE) ? rangeCnt[tid] : 0;
    sd[tid] = v;
    __syncthreads();
    for (int o = 1; o < 128; o <<= 1) {
        int t = (tid >= o) ? sd[tid - o] : 0;
        __syncthreads();
        sd[tid] += t;
        __syncthreads();
    }
    if (tid < NRANGE) { int ex = sd[tid] - v; rangeBase[tid] = ex; gcur[tid] = ex; }
    if (tid == 0) { rangeBase[NRANGE] = NE; rowptr[NN] = NE; }
}

// ---------------------------------------------------------------------------
// P1: coarse bin by dst range, block-synchronous LDS staging (grouped runs).
// ---------------------------------------------------------------------------
__global__ __launch_bounds__(256) void p1_bin_kernel(
    const int* __restrict__ src, const int* __restrict__ dst,
    const float* __restrict__ w, int* __restrict__ gcur,
    int2* __restrict__ ecoarse)
{
    __shared__ int2 stage[1024];
    __shared__ unsigned char sbkt[1024];
    __shared__ int cnt[128], ofs[128], gpos[128], sd[128];

    int tid = threadIdx.x;
    int e0 = blockIdx.x * 1024 + tid * 4;
    int4   s4 = *(const int4*)(src + e0);
    int4   d4 = *(const int4*)(dst + e0);
    float4 w4 = *(const float4*)(w + e0);

    if (tid < 128) cnt[tid] = 0;
    __syncthreads();

    int ss[4] = {s4.x, s4.y, s4.z, s4.w};
    int dd[4] = {d4.x, d4.y, d4.z, d4.w};
    float ww[4] = {w4.x, w4.y, w4.z, w4.w};
    int b[4], p[4];
#pragma unroll
    for (int i = 0; i < 4; ++i) {
        b[i] = dd[i] >> 10;
        p[i] = atomicAdd(&cnt[b[i]], 1);
    }
    __syncthreads();

    int cv = (tid < 128) ? cnt[tid] : 0;
    if (tid < 128) sd[tid] = cv;
    __syncthreads();
    for (int o = 1; o < 128; o <<= 1) {
        int t = (tid >= o && tid < 128) ? sd[tid - o] : 0;
        __syncthreads();
        if (tid < 128) sd[tid] += t;
        __syncthreads();
    }
    if (tid < 128) ofs[tid] = sd[tid] - cv;
    if (tid < NRANGE && cv > 0) gpos[tid] = atomicAdd(&gcur[tid], cv);
    __syncthreads();

#pragma unroll
    for (int i = 0; i < 4; ++i) {
        int slot = ofs[b[i]] + p[i];
        stage[slot] = make_int2(ss[i] | ((dd[i] & 1023) << 17), __float_as_int(ww[i]));
        sbkt[slot] = (unsigned char)b[i];
    }
    __syncthreads();

    for (int j = tid; j < 1024; j += 256) {
        int bb = sbkt[j];
        ecoarse[gpos[bb] + (j - ofs[bb])] = stage[j];
    }
}

// ---------------------------------------------------------------------------
// P2: per-range degree count + LDS scan -> rowptr, then place into the
// range's L2-resident ebuf window. Grid NRANGE.
// ---------------------------------------------------------------------------
__global__ __launch_bounds__(256) void p2_place_kernel(
    const int2* __restrict__ ecoarse, const int* __restrict__ rangeBase,
    int* __restrict__ rowptr, int2* __restrict__ ebuf)
{
    __shared__ int cnt[1024];
    __shared__ int ssum[256];
    int r = blockIdx.x, tid = threadIdx.x;
    int beg = rangeBase[r], end = rangeBase[r + 1];

    for (int i = tid; i < 1024; i += 256) cnt[i] = 0;
    __syncthreads();

    for (int j = beg + tid; j < end; j += 256) {
        int2 rec = ecoarse[j];
        atomicAdd(&cnt[(rec.x >> 17) & 1023], 1);
    }
    __syncthreads();

    int base4 = tid * 4;
    int c0 = cnt[base4], c1 = cnt[base4 + 1], c2 = cnt[base4 + 2], c3 = cnt[base4 + 3];
    int s = c0 + c1 + c2 + c3;
    ssum[tid] = s;
    __syncthreads();
    for (int o = 1; o < 256; o <<= 1) {
        int t = (tid >= o) ? ssum[tid - o] : 0;
        __syncthreads();
        ssum[tid] += t;
        __syncthreads();
    }
    int p0 = beg + ssum[tid] - s;
    int p1 = p0 + c0, p2 = p1 + c1, p3 = p2 + c2;

    int node0 = (r << 10) + base4;
    if (node0 < NN)     rowptr[node0]     = p0;
    if (node0 + 1 < NN) rowptr[node0 + 1] = p1;
    if (node0 + 2 < NN) rowptr[node0 + 2] = p2;
    if (node0 + 3 < NN) rowptr[node0 + 3] = p3;
    cnt[base4] = p0; cnt[base4 + 1] = p1; cnt[base4 + 2] = p2; cnt[base4 + 3] = p3;
    __syncthreads();

    for (int j = beg + tid; j < end; j += 256) {
        int2 rec = ecoarse[j];
        int dl = (rec.x >> 17) & 1023;
        int p = atomicAdd(&cnt[dl], 1);
        ebuf[p] = make_int2(rec.x & 0x1FFFF, rec.y);
    }
}

// ---------------------------------------------------------------------------
// CSR gather over bf16 rows -> bf16 agg. fp32 accumulate, unroll-4 MLP.
// Wave per node, no LDS. Grid 25000.
// ---------------------------------------------------------------------------
__global__ __launch_bounds__(256) void csr_agg_bf16_kernel(
    const unsigned short* __restrict__ hb, const int* __restrict__ rowptr,
    const int2* __restrict__ ebuf, unsigned short* __restrict__ aggb)
{
    int lane = threadIdx.x & 63;
    int node = blockIdx.x * 4 + (threadIdx.x >> 6);
    int beg = __builtin_amdgcn_readfirstlane(rowptr[node]);
    int end = __builtin_amdgcn_readfirstlane(rowptr[node + 1]);

    float a0 = 0.f, a1 = 0.f, a2 = 0.f, a3 = 0.f;
    int j = beg;
    for (; j + 4 <= end; j += 4) {
        int2 e0 = ebuf[j], e1 = ebuf[j + 1], e2 = ebuf[j + 2], e3 = ebuf[j + 3];
        unsigned short u0 = hb[(size_t)e0.x * DD + lane];
        unsigned short u1 = hb[(size_t)e1.x * DD + lane];
        unsigned short u2 = hb[(size_t)e2.x * DD + lane];
        unsigned short u3 = hb[(size_t)e3.x * DD + lane];
        a0 = fmaf(__int_as_float(e0.y), __uint_as_float((unsigned)u0 << 16), a0);
        a1 = fmaf(__int_as_float(e1.y), __uint_as_float((unsigned)u1 << 16), a1);
        a2 = fmaf(__int_as_float(e2.y), __uint_as_float((unsigned)u2 << 16), a2);
        a3 = fmaf(__int_as_float(e3.y), __uint_as_float((unsigned)u3 << 16), a3);
    }
    for (; j < end; ++j) {
        int2 e0 = ebuf[j];
        unsigned short u0 = hb[(size_t)e0.x * DD + lane];
        a0 = fmaf(__int_as_float(e0.y), __uint_as_float((unsigned)u0 << 16), a0);
    }
    aggb[(size_t)node * DD + lane] = f2bf((a0 + a1) + (a2 + a3));
}

// ---------------------------------------------------------------------------
// MFMA dual GEMM (persistent): out16[g*16..][n] = [aggb|hb] @ [Wrel;Wroot]
// + bias (+ReLU). A = 16x128 bf16 (per group), B = 128x64 bf16 (static).
// B fragments held in registers (loaded once); A staged to LDS in MFMA
// fragment order (double-buffered, 1 barrier/group); 4 MFMA/wave/group.
// Layouts (m89/m120-verified): A[m=lane&15][k=quad*8+j],
// B[k=quad*8+j][n=lane&15], D row=quad*4+reg col=lane&15.
// OUT32: store fp32 (layer 3) else bf16.
// ---------------------------------------------------------------------------
template <bool RELU, bool OUT32>
__global__ __launch_bounds__(256) void mfma_gemm_kernel(
    const unsigned short* __restrict__ aggb,
    const unsigned short* __restrict__ hb,
    const float* __restrict__ Wrel,
    const float* __restrict__ brel,
    const float* __restrict__ Wroot,
    void* __restrict__ outp)
{
    __shared__ __align__(16) unsigned short Ast[2][256][8];   // 8 KB

    int tid = threadIdx.x;
    int lane = tid & 63;
    int wv = tid >> 6;            // wave = N-tile (cols 16w..16w+16)
    int quad = lane >> 4;
    int m16 = lane & 15;
    int n = wv * 16 + m16;        // this lane's output column

    // ---- B fragments (static weights) into registers: 4 ksteps x 8 bf16
    bf16x8 bfrag[4];
#pragma unroll
    for (int t = 0; t < 4; ++t) {
#pragma unroll
        for (int j = 0; j < 8; ++j) {
            int k = t * 32 + quad * 8 + j;
            float wval = (k < 64) ? Wrel[k * 64 + n] : Wroot[(k - 64) * 64 + n];
            bfrag[t][j] = (short)f2bf(wval);
        }
    }
    float bias = brel[n];

    // staging role of this thread: kstep ts, row ms, col base c0 (8 bf16 = 16B)
    int ts = tid >> 6;
    int ls = tid & 63;
    int ms = ls & 15;
    int c0 = ts * 32 + (ls >> 4) * 8;
    bool fromAgg = (c0 < 64);
    int cOff = fromAgg ? c0 : (c0 - 64);

    int g = blockIdx.x;
    int buf = 0;
    while (g < NGROUPS) {
        // ---- stage A (16 rows x 128 k, bf16) in fragment order
        {
            size_t row = (size_t)g * 16 + ms;
            const unsigned short* sp = (fromAgg ? aggb : hb) + row * DD + cOff;
            *(uint4*)&Ast[buf][tid][0] = *(const uint4*)sp;
        }
        __syncthreads();

        // ---- 4 chained MFMAs over K=128
        f32x4 c = {0.f, 0.f, 0.f, 0.f};
#pragma unroll
        for (int t = 0; t < 4; ++t) {
            bf16x8 a = *(const bf16x8*)&Ast[buf][t * 64 + lane][0];
            c = __builtin_amdgcn_mfma_f32_16x16x32_bf16(a, bfrag[t], c, 0, 0, 0);
        }

        // ---- epilogue: bias (+ReLU), store
#pragma unroll
        for (int reg = 0; reg < 4; ++reg) {
            int row = quad * 4 + reg;
            size_t node = (size_t)g * 16 + row;
            float v = c[reg] + bias;
            if (RELU) v = fmaxf(v, 0.f);
            if (OUT32) ((float*)outp)[node * DD + n] = v;
            else       ((unsigned short*)outp)[node * DD + n] = f2bf(v);
        }
        g += GG;
        buf ^= 1;
    }
}

extern "C" void kernel_launch(void* const* d_in, const int* in_sizes, int n_in,
                              void* d_out, int out_size, void* d_ws, size_t ws_size,
                              hipStream_t stream)
{
    const float* x     = (const float*)d_in[0];
    const int*   ei    = (const int*)d_in[1];
    const float* w     = (const float*)d_in[2];
    const float* Wrel1 = (const float*)d_in[4];
    const float* brel1 = (const float*)d_in[5];
    const float* Wroot1= (const float*)d_in[6];
    const float* Wrel2 = (const float*)d_in[7];
    const float* brel2 = (const float*)d_in[8];
    const float* Wroot2= (const float*)d_in[9];
    const float* Wrel3 = (const float*)d_in[10];
    const float* brel3 = (const float*)d_in[11];
    const float* Wroot3= (const float*)d_in[12];

    float* out = (float*)d_out;

    // workspace: ebuf | region2 (ecoarse -> xb, after build) | aggb | hb | ints
    char* ws = (char*)d_ws;
    int2*  ebuf    = (int2*)ws;                       ws += (size_t)NE * 8;          // 10.24 MB
    int2*  ecoarse = (int2*)ws;
    unsigned short* xb = (unsigned short*)ws;         ws += (size_t)NN * DD * 2;     // 12.8 MB (>= ecoarse 10.24)
    unsigned short* aggb = (unsigned short*)ws;       ws += (size_t)NN * DD * 2;     // 12.8 MB
    unsigned short* hb = (unsigned short*)ws;         ws += (size_t)NN * DD * 2;     // 12.8 MB
    int*   rowptr  = (int*)ws;                        ws += (size_t)(NN + 1) * 4;
    int*   rangeCnt = (int*)ws;                       ws += (size_t)128 * 4;
    int*   rangeBase = (int*)ws;                      ws += (size_t)128 * 4;
    int*   gcur    = (int*)ws;

    const int* src = ei;
    const int* dst = ei + NE;

    // ---- CSR build (ecoarse region reused as xb afterwards) ----
    hipMemsetAsync(rangeCnt, 0, NRANGE * 4, stream);
    hist2_kernel<<<1250, 256, 0, stream>>>(dst, rangeCnt);
    scan98_kernel<<<1, 128, 0, stream>>>(rangeCnt, rangeBase, gcur, rowptr);
    p1_bin_kernel<<<1250, 256, 0, stream>>>(src, dst, w, gcur, ecoarse);
    p2_place_kernel<<<NRANGE, 256, 0, stream>>>(ecoarse, rangeBase, rowptr, ebuf);

    // ---- xb = bf16(x) (ecoarse dead now) ----
    f32_to_bf16_kernel<<<6250, 256, 0, stream>>>(x, xb);

    // ---- Layer 1: gather(xb)->aggb ; mfma([aggb|xb])->hb (bf16, ReLU) ----
    csr_agg_bf16_kernel<<<NN / 4, 256, 0, stream>>>(xb, rowptr, ebuf, aggb);
    mfma_gemm_kernel<true, false><<<GG, 256, 0, stream>>>(
        aggb, xb, Wrel1, brel1, Wroot1, hb);

    // ---- Layer 2: gather(hb)->aggb ; mfma([aggb|hb])->hb (bf16, ReLU) ----
    csr_agg_bf16_kernel<<<NN / 4, 256, 0, stream>>>(hb, rowptr, ebuf, aggb);
    mfma_gemm_kernel<true, false><<<GG, 256, 0, stream>>>(
        aggb, hb, Wrel2, brel2, Wroot2, hb);

    // ---- Layer 3: gather(hb)->aggb ; mfma([aggb|hb])->out (fp32) ----
    csr_agg_bf16_kernel<<<NN / 4, 256, 0, stream>>>(hb, rowptr, ebuf, aggb);
    mfma_gemm_kernel<false, true><<<GG, 256, 0, stream>>>(
        aggb, hb, Wrel3, brel3, Wroot3, out);
}